// Round 9
// baseline (62.413 us; speedup 1.0000x reference)
//
#include <hip/hip_runtime.h>
#include <hip/hip_bf16.h>
#include <hip/hip_fp16.h>

// Self-attention: B=4, N=4096 (64x64 spatial), C=256, D=32.
//   proj_kernel : MFMA GEMM, 64-row blocks. k,q row-major [B*N][32] f16 (q pre-scaled
//                 by log2e); v tiled vT2[b][n/16][d(32)][n%16].
//   attn_kernel : block = 64 q-rows, 512 threads = 8 waves k-split (512 k each),
//                 swapped-operand MFMA (S^T = K*Q^T, feat^T = V^T*P^T),
//                 2-iteration software pipeline with STATIC slot registers
//                 (macro-generated, no spills), defer-max softmax, padded-LDS
//                 combine, fused output projection + residual epilogue.

#define BB 4
#define NN 4096
#define CC 256
#define DD 32
#define LOG2E 1.44269504088896340736f
#define THR2 11.0f

typedef _Float16 half_t;
typedef _Float16 half2_t __attribute__((ext_vector_type(2)));
typedef _Float16 half4_t __attribute__((ext_vector_type(4)));
typedef _Float16 half8_t __attribute__((ext_vector_type(8)));
typedef float f32x4 __attribute__((ext_vector_type(4)));

#define MFMA_QK(a, b, c) __builtin_amdgcn_mfma_f32_16x16x32_f16(a, b, c, 0, 0, 0)
#define MFMA_PV(a, b, c) __builtin_amdgcn_mfma_f32_16x16x16f16(a, b, c, 0, 0, 0)

static __device__ inline float fexp2(float x) {
#if __has_builtin(__builtin_amdgcn_exp2f)
    return __builtin_amdgcn_exp2f(x);
#else
    return exp2f(x);
#endif
}

// ---------------- Kernel 1: fused QKV projection (MFMA) ----------------
// grid 256 blocks x 512 threads (8 waves); block = 64 rows of x. (validated ~2.5us)
__global__ __launch_bounds__(512) void proj_kernel(
    const float* __restrict__ x,
    const float* __restrict__ Wk, const float* __restrict__ bk,
    const float* __restrict__ Wq, const float* __restrict__ bq,
    const float* __restrict__ Wv, const float* __restrict__ bv,
    half_t* __restrict__ k_ws, half_t* __restrict__ q_ws, half_t* __restrict__ vT2)
{
    __shared__ half_t xs16[64][264];  // x tile f16 (rows 16B-aligned)
    __shared__ half_t Wt[96][264];    // [Wk|Wq|Wv]^T : Wt[wcol][kdim]

    const int t = threadIdx.x;
    const int row0 = blockIdx.x * 64;   // 64 | 4096: never straddles batch

    // stage x tile [64][256] fp32 -> f16
    const float4* x4 = reinterpret_cast<const float4*>(x) + (size_t)row0 * 64;
    for (int idx = t; idx < 64 * 64; idx += 512) {
        int r = idx >> 6, c4 = idx & 63;
        float4 v = x4[r * 64 + c4];
        half4_t h;
        h[0] = (half_t)v.x; h[1] = (half_t)v.y; h[2] = (half_t)v.z; h[3] = (half_t)v.w;
        *reinterpret_cast<half4_t*>(&xs16[r][c4 * 4]) = h;
    }

    // stage W^T (q columns pre-scaled by log2e)
    for (int idx = t; idx < 3072; idx += 512) {
        int cp = idx & 127;           // c-pair
        int rest = idx >> 7;          // 0..23
        int d4 = (rest & 7) * 4;
        int mat = rest >> 3;          // 0:k 1:q 2:v
        const float* Wm = (mat == 0) ? Wk : ((mat == 1) ? Wq : Wv);
        const float sc = (mat == 1) ? LOG2E : 1.0f;
        float4 w0 = *reinterpret_cast<const float4*>(Wm + (2 * cp) * DD + d4);
        float4 w1 = *reinterpret_cast<const float4*>(Wm + (2 * cp + 1) * DD + d4);
        int rbase = mat * 32 + d4;
        half2_t h;
        h[0] = (half_t)(w0.x * sc); h[1] = (half_t)(w1.x * sc);
        *reinterpret_cast<half2_t*>(&Wt[rbase + 0][2 * cp]) = h;
        h[0] = (half_t)(w0.y * sc); h[1] = (half_t)(w1.y * sc);
        *reinterpret_cast<half2_t*>(&Wt[rbase + 1][2 * cp]) = h;
        h[0] = (half_t)(w0.z * sc); h[1] = (half_t)(w1.z * sc);
        *reinterpret_cast<half2_t*>(&Wt[rbase + 2][2 * cp]) = h;
        h[0] = (half_t)(w0.w * sc); h[1] = (half_t)(w1.w * sc);
        *reinterpret_cast<half2_t*>(&Wt[rbase + 3][2 * cp]) = h;
    }
    __syncthreads();

    const int w = t >> 6, lane = t & 63;
    const int c = lane & 15, g = lane >> 4;
    const int rt = w >> 1;            // row tile 0..3
    const int ct0 = (w & 1) * 3;      // col tiles ct0..ct0+2

    f32x4 acc[3];
#pragma unroll
    for (int j = 0; j < 3; ++j) acc[j] = (f32x4){0.f, 0.f, 0.f, 0.f};

#pragma unroll
    for (int kk = 0; kk < 8; ++kk) {
        const int k0 = kk * 32 + g * 8;
        half8_t bfrag = *reinterpret_cast<const half8_t*>(&xs16[rt * 16 + c][k0]);
#pragma unroll
        for (int j = 0; j < 3; ++j) {
            half8_t afrag = *reinterpret_cast<const half8_t*>(&Wt[(ct0 + j) * 16 + c][k0]);
            acc[j] = MFMA_QK(afrag, bfrag, acc[j]);
        }
    }

    // store: lane holds C[xrow = rt*16+c][wcol = ct*16+4g+i]
    const int grow = row0 + rt * 16 + c;
#pragma unroll
    for (int j = 0; j < 3; ++j) {
        const int ct = ct0 + j;
        const int mat = ct >> 1;           // 0:k 1:q 2:v
        const float* bm = (mat == 0) ? bk : ((mat == 1) ? bq : bv);
        float4 bb = *reinterpret_cast<const float4*>(bm + (ct & 1) * 16 + g * 4);
        if (mat < 2) {
            const float bsc = (mat == 1) ? LOG2E : 1.0f;
            half_t* dst = (mat == 0) ? k_ws : q_ws;
            half4_t h;
            h[0] = (half_t)(acc[j][0] + bb.x * bsc);
            h[1] = (half_t)(acc[j][1] + bb.y * bsc);
            h[2] = (half_t)(acc[j][2] + bb.z * bsc);
            h[3] = (half_t)(acc[j][3] + bb.w * bsc);
            *reinterpret_cast<half4_t*>(dst + (size_t)grow * DD + (ct & 1) * 16 + g * 4) = h;
        } else {
            // vT2[(row0>>4)+rt][d][n%16], d = (ct&1)*16+g*4+i, n%16 = c
            const size_t tbase = ((size_t)(row0 >> 4) + rt) * 512;
            const int d0 = (ct & 1) * 16 + g * 4;
            vT2[tbase + (size_t)(d0 + 0) * 16 + c] = (half_t)(acc[j][0] + bb.x);
            vT2[tbase + (size_t)(d0 + 1) * 16 + c] = (half_t)(acc[j][1] + bb.y);
            vT2[tbase + (size_t)(d0 + 2) * 16 + c] = (half_t)(acc[j][2] + bb.z);
            vT2[tbase + (size_t)(d0 + 3) * 16 + c] = (half_t)(acc[j][3] + bb.w);
        }
    }
}

// ---------------- Kernel 2: flash attention + output projection ----------------
// grid 256 blocks (b*64+qb) x 512 threads (8 waves). Block = 64 q rows (4 tiles/wave).
// Wave w: k in [w*512, (w+1)*512), 2 k-tiles of 16 per step, 16 steps,
// 2-step-deep static-register software pipeline (slots A/B, macro-generated).
__global__ __launch_bounds__(512, 4) void attn_kernel(
    const half_t* __restrict__ k_ws, const half_t* __restrict__ q_ws,
    const half_t* __restrict__ vT2,
    const float* __restrict__ x, const float* __restrict__ Wo,
    const float* __restrict__ bo, const float* __restrict__ gamma,
    float* __restrict__ out)
{
    __shared__ float acc_l[8][64][33];    // 67.6 KB, 33-pad -> conflict-free combine
    __shared__ float m_l[8][4][16];       // 2 KB
    __shared__ float s_l[8][4][16];       // 2 KB
    __shared__ float feat_lds[64][33];    // 8.4 KB   (total ~80 KB -> 2 blocks/CU)

    const int tid = threadIdx.x;
    const int w = tid >> 6, lane = tid & 63;
    const int q = lane & 15, g = lane >> 4;
    const int b = blockIdx.x >> 6, qb = blockIdx.x & 63;
    const int q0 = qb * 64;

    // Q fragments (B-operand of S^T = K*Q^T), pre-scaled by log2e
    half8_t qf[4];
#pragma unroll
    for (int t = 0; t < 4; ++t)
        qf[t] = *reinterpret_cast<const half8_t*>(
            q_ws + (size_t)(b * NN + q0 + t * 16 + q) * DD + g * 8);

    float m[4], ssum[4];
    f32x4 accd0[4], accd1[4];
#pragma unroll
    for (int t = 0; t < 4; ++t) {
        m[t] = -3.0e38f; ssum[t] = 0.f;
        accd0[t] = (f32x4){0.f, 0.f, 0.f, 0.f};
        accd1[t] = (f32x4){0.f, 0.f, 0.f, 0.f};
    }

    const half_t* kbase = k_ws + ((size_t)b * NN + q) * DD + g * 8;
    // vT2 tile = 512 halves [d(32)][n%16]; lane reads d={q,16+q}, n%16 = g*4..+3
    const half_t* vb = vT2 + (size_t)b * 256 * 512 + q * 16 + g * 4;

    const int ktbase = w * 32;   // 32 k-tiles per wave (512 k), 2 per step

    // ---- 2-deep static pipeline: slots A (even steps) and B (odd steps) ----
    half8_t kc0A, kc1A, kc0B, kc1B;
    half4_t va0A, va1A, vc0A, vc1A;
    half4_t va0B, va1B, vc0B, vc1B;

#define LOADK(S, kt)                                                                   \
    kc0##S = *reinterpret_cast<const half8_t*>(kbase + (size_t)((kt) + 0) * 16 * DD);  \
    kc1##S = *reinterpret_cast<const half8_t*>(kbase + (size_t)((kt) + 1) * 16 * DD);
#define LOADV(S, kt)                                                                   \
    va0##S = *reinterpret_cast<const half4_t*>(vb + (size_t)((kt) + 0) * 512);         \
    va1##S = *reinterpret_cast<const half4_t*>(vb + (size_t)((kt) + 0) * 512 + 256);   \
    vc0##S = *reinterpret_cast<const half4_t*>(vb + (size_t)((kt) + 1) * 512);         \
    vc1##S = *reinterpret_cast<const half4_t*>(vb + (size_t)((kt) + 1) * 512 + 256);

    LOADK(A, ktbase + 0) LOADV(A, ktbase + 0)
    LOADK(B, ktbase + 2) LOADV(B, ktbase + 2)

#define STEP(IT, S)                                                                    \
    {                                                                                  \
        const f32x4 z = {0.f, 0.f, 0.f, 0.f};                                          \
        f32x4 s0[4], s1[4];                                                            \
        _Pragma("unroll")                                                              \
        for (int t = 0; t < 4; ++t) {                                                  \
            s0[t] = MFMA_QK(kc0##S, qf[t], z);                                         \
            s1[t] = MFMA_QK(kc1##S, qf[t], z);                                         \
        }                                                                              \
        if ((IT) < 14) { LOADK(S, ktbase + ((IT) + 2) * 2) }                           \
        float tmax[4];                                                                 \
        bool need = false;                                                             \
        _Pragma("unroll")                                                              \
        for (int t = 0; t < 4; ++t) {                                                  \
            float t0 = fmaxf(fmaxf(s0[t][0], s0[t][1]), fmaxf(s0[t][2], s0[t][3]));    \
            float t1 = fmaxf(fmaxf(s1[t][0], s1[t][1]), fmaxf(s1[t][2], s1[t][3]));    \
            tmax[t] = fmaxf(t0, t1);                                                   \
            need = need || (tmax[t] > m[t] + THR2);                                    \
        }                                                                              \
        if (__any(need)) {                                                             \
            _Pragma("unroll")                                                          \
            for (int t = 0; t < 4; ++t) {                                              \
                float rmax = tmax[t];                                                  \
                rmax = fmaxf(rmax, __shfl_xor(rmax, 16));                              \
                rmax = fmaxf(rmax, __shfl_xor(rmax, 32));                              \
                float mn = fmaxf(m[t], rmax);                                          \
                float sc = fexp2(m[t] - mn);                                           \
                ssum[t] *= sc;                                                         \
                accd0[t] *= sc;                                                        \
                accd1[t] *= sc;                                                        \
                m[t] = mn;                                                             \
            }                                                                          \
        }                                                                              \
        _Pragma("unroll")                                                              \
        for (int t = 0; t < 4; ++t) {                                                  \
            float p00 = fexp2(s0[t][0] - m[t]), p01 = fexp2(s0[t][1] - m[t]);          \
            float p02 = fexp2(s0[t][2] - m[t]), p03 = fexp2(s0[t][3] - m[t]);          \
            float p10 = fexp2(s1[t][0] - m[t]), p11 = fexp2(s1[t][1] - m[t]);          \
            float p12 = fexp2(s1[t][2] - m[t]), p13 = fexp2(s1[t][3] - m[t]);          \
            ssum[t] += ((p00 + p01) + (p02 + p03)) + ((p10 + p11) + (p12 + p13));      \
            half4_t pf0, pf1;                                                          \
            pf0[0] = (half_t)p00; pf0[1] = (half_t)p01;                                \
            pf0[2] = (half_t)p02; pf0[3] = (half_t)p03;                                \
            pf1[0] = (half_t)p10; pf1[1] = (half_t)p11;                                \
            pf1[2] = (half_t)p12; pf1[3] = (half_t)p13;                                \
            accd0[t] = MFMA_PV(va0##S, pf0, accd0[t]);                                 \
            accd1[t] = MFMA_PV(va1##S, pf0, accd1[t]);                                 \
            accd0[t] = MFMA_PV(vc0##S, pf1, accd0[t]);                                 \
            accd1[t] = MFMA_PV(vc1##S, pf1, accd1[t]);                                 \
        }                                                                              \
        if ((IT) < 14) { LOADV(S, ktbase + ((IT) + 2) * 2) }                           \
    }

    STEP(0, A)  STEP(1, B)  STEP(2, A)  STEP(3, B)
    STEP(4, A)  STEP(5, B)  STEP(6, A)  STEP(7, B)
    STEP(8, A)  STEP(9, B)  STEP(10, A) STEP(11, B)
    STEP(12, A) STEP(13, B) STEP(14, A) STEP(15, B)

#undef STEP
#undef LOADK
#undef LOADV

    // fold lane-local ssum to row sums
#pragma unroll
    for (int t = 0; t < 4; ++t) {
        ssum[t] += __shfl_xor(ssum[t], 16);
        ssum[t] += __shfl_xor(ssum[t], 32);
    }

    if (lane < 16) {
#pragma unroll
        for (int t = 0; t < 4; ++t) { m_l[w][t][lane] = m[t]; s_l[w][t][lane] = ssum[t]; }
    }
#pragma unroll
    for (int t = 0; t < 4; ++t)
#pragma unroll
        for (int i = 0; i < 4; ++i) {
            acc_l[w][lane][t * 8 + i] = accd0[t][i];
            acc_l[w][lane][t * 8 + 4 + i] = accd1[t][i];
        }
    __syncthreads();

    // waves 0..3 combine the 8 k-splits; wave w handles q-tile t=w
    if (w < 4) {
        const int t = w;
        float M = m_l[0][t][q];
#pragma unroll
        for (int ww = 1; ww < 8; ++ww) M = fmaxf(M, m_l[ww][t][q]);
        float SS = 0.f;
        float f[8] = {0.f, 0.f, 0.f, 0.f, 0.f, 0.f, 0.f, 0.f};
#pragma unroll
        for (int ww = 0; ww < 8; ++ww) {
            float sc = fexp2(m_l[ww][t][q] - M);
            SS += s_l[ww][t][q] * sc;
#pragma unroll
            for (int i = 0; i < 8; ++i) f[i] += acc_l[ww][lane][t * 8 + i] * sc;
        }
        float inv = 1.0f / SS;
#pragma unroll
        for (int i = 0; i < 4; ++i) {
            feat_lds[t * 16 + q][g * 4 + i] = f[i] * inv;
            feat_lds[t * 16 + q][16 + g * 4 + i] = f[4 + i] * inv;
        }
    }
    __syncthreads();

    // epilogue: 64 rows x 256 cols; c = tid&255, rh = tid>>8 -> 32 rows each
    const int c = tid & 255, rh = tid >> 8;
    float wv[32];
#pragma unroll
    for (int d = 0; d < DD; ++d) wv[d] = Wo[d * CC + c];
    const float gam = gamma[0];
    const float bias = bo[c];

#pragma unroll
    for (int chunk = 0; chunk < 4; ++chunk) {
        const int r0 = rh * 32 + chunk * 8;
        float oacc[8] = {0.f, 0.f, 0.f, 0.f, 0.f, 0.f, 0.f, 0.f};
#pragma unroll
        for (int d = 0; d < DD; ++d) {
            float wvd = wv[d];
#pragma unroll
            for (int r = 0; r < 8; ++r) oacc[r] += feat_lds[r0 + r][d] * wvd;
        }
        const size_t base = ((size_t)b * NN + (size_t)q0 + r0) * CC + c;
        const float* xr = x + base;
        float* outr = out + base;
#pragma unroll
        for (int r = 0; r < 8; ++r)
            outr[(size_t)r * CC] = gam * (oacc[r] + bias) + xr[(size_t)r * CC];
    }
}

// ---------------- launch ----------------
extern "C" void kernel_launch(void* const* d_in, const int* in_sizes, int n_in,
                              void* d_out, int out_size, void* d_ws, size_t ws_size,
                              hipStream_t stream) {
    const float* x  = (const float*)d_in[0];
    const float* Wk = (const float*)d_in[1];
    const float* bk = (const float*)d_in[2];
    const float* Wq = (const float*)d_in[3];
    const float* bq = (const float*)d_in[4];
    const float* Wv = (const float*)d_in[5];
    const float* bv = (const float*)d_in[6];
    const float* Wo = (const float*)d_in[7];
    const float* bo = (const float*)d_in[8];
    const float* gamma = (const float*)d_in[9];
    float* out = (float*)d_out;

    half_t* k_ws  = (half_t*)d_ws;
    half_t* q_ws  = k_ws + (size_t)BB * NN * DD;
    half_t* vT2   = q_ws + (size_t)BB * NN * DD;

    proj_kernel<<<256, 512, 0, stream>>>(x, Wk, bk, Wq, bq, Wv, bv, k_ws, q_ws, vT2);
    attn_kernel<<<256, 512, 0, stream>>>(k_ws, q_ws, vT2, x, Wo, bo, gamma, out);
}

// Round 10
// 40.379 us; speedup vs baseline: 1.5457x; 1.5457x over previous
//
#include <hip/hip_runtime.h>
#include <hip/hip_bf16.h>
#include <hip/hip_fp16.h>

// Self-attention: B=4, N=4096 (64x64 spatial), C=256, D=32.
//   proj_kernel : MFMA GEMM, 64-row blocks (validated ~2.5us). k,q row-major
//                 [B*N][32] f16 (q pre-scaled by log2e); v tiled vT2[b][n/16][d][n%16].
//   attn_kernel : block = 64 q-rows, 512 threads = 8 waves k-split (512 k each),
//                 swapped-operand MFMA (S^T = K*Q^T, feat^T = V^T*P^T), simple
//                 1-deep register prefetch (R6 structure, the validated best),
//                 defer-max softmax, PADDED combine (bank-conflict-free),
//                 MFMA epilogue: O = gamma*(feat@Wo + bo) + x via Wo^T staged in LDS.

#define BB 4
#define NN 4096
#define CC 256
#define DD 32
#define LOG2E 1.44269504088896340736f
#define THR2 11.0f

typedef _Float16 half_t;
typedef _Float16 half2_t __attribute__((ext_vector_type(2)));
typedef _Float16 half4_t __attribute__((ext_vector_type(4)));
typedef _Float16 half8_t __attribute__((ext_vector_type(8)));
typedef float f32x4 __attribute__((ext_vector_type(4)));

#define MFMA_QK(a, b, c) __builtin_amdgcn_mfma_f32_16x16x32_f16(a, b, c, 0, 0, 0)
#define MFMA_PV(a, b, c) __builtin_amdgcn_mfma_f32_16x16x16f16(a, b, c, 0, 0, 0)

static __device__ inline float fexp2(float x) {
#if __has_builtin(__builtin_amdgcn_exp2f)
    return __builtin_amdgcn_exp2f(x);
#else
    return exp2f(x);
#endif
}

// ---------------- Kernel 1: fused QKV projection (MFMA) ----------------
// grid 256 blocks x 512 threads (8 waves); block = 64 rows of x.
__global__ __launch_bounds__(512) void proj_kernel(
    const float* __restrict__ x,
    const float* __restrict__ Wk, const float* __restrict__ bk,
    const float* __restrict__ Wq, const float* __restrict__ bq,
    const float* __restrict__ Wv, const float* __restrict__ bv,
    half_t* __restrict__ k_ws, half_t* __restrict__ q_ws, half_t* __restrict__ vT2)
{
    __shared__ half_t xs16[64][264];  // x tile f16 (rows 16B-aligned)
    __shared__ half_t Wt[96][264];    // [Wk|Wq|Wv]^T : Wt[wcol][kdim]

    const int t = threadIdx.x;
    const int row0 = blockIdx.x * 64;   // 64 | 4096: never straddles batch

    // stage x tile [64][256] fp32 -> f16
    const float4* x4 = reinterpret_cast<const float4*>(x) + (size_t)row0 * 64;
    for (int idx = t; idx < 64 * 64; idx += 512) {
        int r = idx >> 6, c4 = idx & 63;
        float4 v = x4[r * 64 + c4];
        half4_t h;
        h[0] = (half_t)v.x; h[1] = (half_t)v.y; h[2] = (half_t)v.z; h[3] = (half_t)v.w;
        *reinterpret_cast<half4_t*>(&xs16[r][c4 * 4]) = h;
    }

    // stage W^T (q columns pre-scaled by log2e)
    for (int idx = t; idx < 3072; idx += 512) {
        int cp = idx & 127;           // c-pair
        int rest = idx >> 7;          // 0..23
        int d4 = (rest & 7) * 4;
        int mat = rest >> 3;          // 0:k 1:q 2:v
        const float* Wm = (mat == 0) ? Wk : ((mat == 1) ? Wq : Wv);
        const float sc = (mat == 1) ? LOG2E : 1.0f;
        float4 w0 = *reinterpret_cast<const float4*>(Wm + (2 * cp) * DD + d4);
        float4 w1 = *reinterpret_cast<const float4*>(Wm + (2 * cp + 1) * DD + d4);
        int rbase = mat * 32 + d4;
        half2_t h;
        h[0] = (half_t)(w0.x * sc); h[1] = (half_t)(w1.x * sc);
        *reinterpret_cast<half2_t*>(&Wt[rbase + 0][2 * cp]) = h;
        h[0] = (half_t)(w0.y * sc); h[1] = (half_t)(w1.y * sc);
        *reinterpret_cast<half2_t*>(&Wt[rbase + 1][2 * cp]) = h;
        h[0] = (half_t)(w0.z * sc); h[1] = (half_t)(w1.z * sc);
        *reinterpret_cast<half2_t*>(&Wt[rbase + 2][2 * cp]) = h;
        h[0] = (half_t)(w0.w * sc); h[1] = (half_t)(w1.w * sc);
        *reinterpret_cast<half2_t*>(&Wt[rbase + 3][2 * cp]) = h;
    }
    __syncthreads();

    const int w = t >> 6, lane = t & 63;
    const int c = lane & 15, g = lane >> 4;
    const int rt = w >> 1;            // row tile 0..3
    const int ct0 = (w & 1) * 3;      // col tiles ct0..ct0+2

    f32x4 acc[3];
#pragma unroll
    for (int j = 0; j < 3; ++j) acc[j] = (f32x4){0.f, 0.f, 0.f, 0.f};

#pragma unroll
    for (int kk = 0; kk < 8; ++kk) {
        const int k0 = kk * 32 + g * 8;
        half8_t bfrag = *reinterpret_cast<const half8_t*>(&xs16[rt * 16 + c][k0]);
#pragma unroll
        for (int j = 0; j < 3; ++j) {
            half8_t afrag = *reinterpret_cast<const half8_t*>(&Wt[(ct0 + j) * 16 + c][k0]);
            acc[j] = MFMA_QK(afrag, bfrag, acc[j]);
        }
    }

    // store: lane holds C[xrow = rt*16+c][wcol = ct*16+4g+i]
    const int grow = row0 + rt * 16 + c;
#pragma unroll
    for (int j = 0; j < 3; ++j) {
        const int ct = ct0 + j;
        const int mat = ct >> 1;           // 0:k 1:q 2:v
        const float* bm = (mat == 0) ? bk : ((mat == 1) ? bq : bv);
        float4 bb = *reinterpret_cast<const float4*>(bm + (ct & 1) * 16 + g * 4);
        if (mat < 2) {
            const float bsc = (mat == 1) ? LOG2E : 1.0f;
            half_t* dst = (mat == 0) ? k_ws : q_ws;
            half4_t h;
            h[0] = (half_t)(acc[j][0] + bb.x * bsc);
            h[1] = (half_t)(acc[j][1] + bb.y * bsc);
            h[2] = (half_t)(acc[j][2] + bb.z * bsc);
            h[3] = (half_t)(acc[j][3] + bb.w * bsc);
            *reinterpret_cast<half4_t*>(dst + (size_t)grow * DD + (ct & 1) * 16 + g * 4) = h;
        } else {
            // vT2[(row0>>4)+rt][d][n%16], d = (ct&1)*16+g*4+i, n%16 = c
            const size_t tbase = ((size_t)(row0 >> 4) + rt) * 512;
            const int d0 = (ct & 1) * 16 + g * 4;
            vT2[tbase + (size_t)(d0 + 0) * 16 + c] = (half_t)(acc[j][0] + bb.x);
            vT2[tbase + (size_t)(d0 + 1) * 16 + c] = (half_t)(acc[j][1] + bb.y);
            vT2[tbase + (size_t)(d0 + 2) * 16 + c] = (half_t)(acc[j][2] + bb.z);
            vT2[tbase + (size_t)(d0 + 3) * 16 + c] = (half_t)(acc[j][3] + bb.w);
        }
    }
}

// ---------------- Kernel 2: flash attention + output projection ----------------
// grid 256 blocks (b*64+qb) x 512 threads (8 waves). Block = 64 q rows (4 tiles/wave).
// Wave w: k in [w*512, (w+1)*512), 2 k-tiles of 16 per iter, 16 iters, 1-deep prefetch.
__global__ __launch_bounds__(512) void attn_kernel(
    const half_t* __restrict__ k_ws, const half_t* __restrict__ q_ws,
    const half_t* __restrict__ vT2,
    const float* __restrict__ x, const float* __restrict__ Wo,
    const float* __restrict__ bo, const float* __restrict__ gamma,
    float* __restrict__ out)
{
    __shared__ float acc_l[8][64][33];    // 67.6 KB, 33-pad -> conflict-free combine
    __shared__ float m_l[8][4][16];       // 2 KB
    __shared__ float s_l[8][4][16];       // 2 KB
    __shared__ half_t feat_h[64 * 40];    // 5 KB  feat f16, 40-halves rows (80B, aligned)
    __shared__ half_t woT[256 * 40];      // 20 KB Wo^T f16: woT[c*40+d]

    const int tid = threadIdx.x;
    const int w = tid >> 6, lane = tid & 63;
    const int q = lane & 15, g = lane >> 4;
    const int b = blockIdx.x >> 6, qb = blockIdx.x & 63;
    const int q0 = qb * 64;

    // stage Wo^T as f16 (coalesced reads; 8192 elements)
#pragma unroll
    for (int it = 0; it < 16; ++it) {
        int idx = tid + it * 512;
        int c = idx & 255, d = idx >> 8;
        woT[c * 40 + d] = (half_t)Wo[d * CC + c];
    }

    // Q fragments (B-operand of S^T = K*Q^T), pre-scaled by log2e
    half8_t qf[4];
#pragma unroll
    for (int t = 0; t < 4; ++t)
        qf[t] = *reinterpret_cast<const half8_t*>(
            q_ws + (size_t)(b * NN + q0 + t * 16 + q) * DD + g * 8);

    float m[4], ssum[4];
    f32x4 accd0[4], accd1[4];
#pragma unroll
    for (int t = 0; t < 4; ++t) {
        m[t] = -3.0e38f; ssum[t] = 0.f;
        accd0[t] = (f32x4){0.f, 0.f, 0.f, 0.f};
        accd1[t] = (f32x4){0.f, 0.f, 0.f, 0.f};
    }

    const half_t* kbase = k_ws + ((size_t)b * NN + q) * DD + g * 8;
    // vT2 tile = 512 halves [d(32)][n%16]; lane reads d={q,16+q}, n%16 = g*4..+3
    const half_t* vb = vT2 + (size_t)b * 256 * 512 + q * 16 + g * 4;

    const int ktbase = w * 32;

    // prologue: iteration 0's K and V fragments
    half8_t kc0 = *reinterpret_cast<const half8_t*>(kbase + (size_t)(ktbase + 0) * 16 * DD);
    half8_t kc1 = *reinterpret_cast<const half8_t*>(kbase + (size_t)(ktbase + 1) * 16 * DD);
    half4_t va0 = *reinterpret_cast<const half4_t*>(vb + (size_t)(ktbase + 0) * 512);
    half4_t va1 = *reinterpret_cast<const half4_t*>(vb + (size_t)(ktbase + 0) * 512 + 256);
    half4_t vc0 = *reinterpret_cast<const half4_t*>(vb + (size_t)(ktbase + 1) * 512);
    half4_t vc1 = *reinterpret_cast<const half4_t*>(vb + (size_t)(ktbase + 1) * 512 + 256);

    for (int it = 0; it < 16; ++it) {
        const int kt = ktbase + it * 2;
        const int ktn = (it < 15) ? (kt + 2) : kt;

        // prefetch next iteration's K and V fragments
        half8_t kn0 = *reinterpret_cast<const half8_t*>(kbase + (size_t)(ktn + 0) * 16 * DD);
        half8_t kn1 = *reinterpret_cast<const half8_t*>(kbase + (size_t)(ktn + 1) * 16 * DD);
        half4_t wa0 = *reinterpret_cast<const half4_t*>(vb + (size_t)(ktn + 0) * 512);
        half4_t wa1 = *reinterpret_cast<const half4_t*>(vb + (size_t)(ktn + 0) * 512 + 256);
        half4_t wc0 = *reinterpret_cast<const half4_t*>(vb + (size_t)(ktn + 1) * 512);
        half4_t wc1 = *reinterpret_cast<const half4_t*>(vb + (size_t)(ktn + 1) * 512 + 256);

        // QK^T: 8 MFMAs (4 q-tiles x 2 k-tiles) on resident K
        f32x4 z = {0.f, 0.f, 0.f, 0.f};
        f32x4 s0[4], s1[4];
#pragma unroll
        for (int t = 0; t < 4; ++t) {
            s0[t] = MFMA_QK(kc0, qf[t], z);
            s1[t] = MFMA_QK(kc1, qf[t], z);
        }

        float tmax[4];
        bool need = false;
#pragma unroll
        for (int t = 0; t < 4; ++t) {
            float t0 = fmaxf(fmaxf(s0[t][0], s0[t][1]), fmaxf(s0[t][2], s0[t][3]));
            float t1 = fmaxf(fmaxf(s1[t][0], s1[t][1]), fmaxf(s1[t][2], s1[t][3]));
            tmax[t] = fmaxf(t0, t1);
            need = need || (tmax[t] > m[t] + THR2);
        }

        // defer-max: rescale only when some lane/tile exceeds headroom
        if (__any(need)) {
#pragma unroll
            for (int t = 0; t < 4; ++t) {
                float rmax = tmax[t];
                rmax = fmaxf(rmax, __shfl_xor(rmax, 16));
                rmax = fmaxf(rmax, __shfl_xor(rmax, 32));
                float mn = fmaxf(m[t], rmax);
                float sc = fexp2(m[t] - mn);
                ssum[t] *= sc;
                accd0[t] *= sc;
                accd1[t] *= sc;
                m[t] = mn;
            }
        }

        // softmax (log2 domain) + PV per q-tile
#pragma unroll
        for (int t = 0; t < 4; ++t) {
            float p00 = fexp2(s0[t][0] - m[t]), p01 = fexp2(s0[t][1] - m[t]);
            float p02 = fexp2(s0[t][2] - m[t]), p03 = fexp2(s0[t][3] - m[t]);
            float p10 = fexp2(s1[t][0] - m[t]), p11 = fexp2(s1[t][1] - m[t]);
            float p12 = fexp2(s1[t][2] - m[t]), p13 = fexp2(s1[t][3] - m[t]);
            ssum[t] += ((p00 + p01) + (p02 + p03)) + ((p10 + p11) + (p12 + p13));

            half4_t pf0, pf1;
            pf0[0] = (half_t)p00; pf0[1] = (half_t)p01; pf0[2] = (half_t)p02; pf0[3] = (half_t)p03;
            pf1[0] = (half_t)p10; pf1[1] = (half_t)p11; pf1[2] = (half_t)p12; pf1[3] = (half_t)p13;

            accd0[t] = MFMA_PV(va0, pf0, accd0[t]);
            accd1[t] = MFMA_PV(va1, pf0, accd1[t]);
            accd0[t] = MFMA_PV(vc0, pf1, accd0[t]);
            accd1[t] = MFMA_PV(vc1, pf1, accd1[t]);
        }

        kc0 = kn0; kc1 = kn1;
        va0 = wa0; va1 = wa1; vc0 = wc0; vc1 = wc1;
    }

    // fold lane-local ssum to row sums
#pragma unroll
    for (int t = 0; t < 4; ++t) {
        ssum[t] += __shfl_xor(ssum[t], 16);
        ssum[t] += __shfl_xor(ssum[t], 32);
    }

    if (lane < 16) {
#pragma unroll
        for (int t = 0; t < 4; ++t) { m_l[w][t][lane] = m[t]; s_l[w][t][lane] = ssum[t]; }
    }
#pragma unroll
    for (int t = 0; t < 4; ++t)
#pragma unroll
        for (int i = 0; i < 4; ++i) {
            acc_l[w][lane][t * 8 + i] = accd0[t][i];
            acc_l[w][lane][t * 8 + 4 + i] = accd1[t][i];
        }
    __syncthreads();

    // waves 0..3 combine the 8 k-splits; wave w handles q-tile t=w.
    // acc_l lane-stride 33 words -> conflict-free. feat written as f16 in the
    // B-fragment layout for the epilogue MFMA.
    if (w < 4) {
        const int t = w;
        float M = m_l[0][t][q];
#pragma unroll
        for (int ww = 1; ww < 8; ++ww) M = fmaxf(M, m_l[ww][t][q]);
        float SS = 0.f;
        float f[8] = {0.f, 0.f, 0.f, 0.f, 0.f, 0.f, 0.f, 0.f};
#pragma unroll
        for (int ww = 0; ww < 8; ++ww) {
            float sc = fexp2(m_l[ww][t][q] - M);
            SS += s_l[ww][t][q] * sc;
#pragma unroll
            for (int i = 0; i < 8; ++i) f[i] += acc_l[ww][lane][t * 8 + i] * sc;
        }
        float inv = 1.0f / SS;
        half4_t h0, h1;
#pragma unroll
        for (int i = 0; i < 4; ++i) { h0[i] = (half_t)(f[i] * inv); h1[i] = (half_t)(f[4 + i] * inv); }
        *reinterpret_cast<half4_t*>(&feat_h[(t * 16 + q) * 40 + g * 4]) = h0;
        *reinterpret_cast<half4_t*>(&feat_h[(t * 16 + q) * 40 + 16 + g * 4]) = h1;
    }
    __syncthreads();

    // ---- MFMA epilogue: O[r][c] = gamma*(feat@Wo + bo) + x ----
    // O = MFMA_QK(kf=WoT rows (c), qf=feat rows (r)): lane(q,g) -> O[rt*16+q][ct*16+4g+i]
    // wave w handles ctiles {2w, 2w+1} x rtiles 0..3.
    const float gam = gamma[0];
#pragma unroll
    for (int j = 0; j < 2; ++j) {
        const int ct = w * 2 + j;
        half8_t kfe = *reinterpret_cast<const half8_t*>(&woT[(ct * 16 + q) * 40 + g * 8]);
        float4 bb4 = *reinterpret_cast<const float4*>(bo + ct * 16 + g * 4);
#pragma unroll
        for (int rt = 0; rt < 4; ++rt) {
            half8_t qfe = *reinterpret_cast<const half8_t*>(&feat_h[(rt * 16 + q) * 40 + g * 8]);
            f32x4 z = {0.f, 0.f, 0.f, 0.f};
            f32x4 o = MFMA_QK(kfe, qfe, z);
            const size_t base = ((size_t)b * NN + q0 + rt * 16 + q) * CC + ct * 16 + g * 4;
            float4 xv = *reinterpret_cast<const float4*>(x + base);
            float4 ov;
            ov.x = gam * (o[0] + bb4.x) + xv.x;
            ov.y = gam * (o[1] + bb4.y) + xv.y;
            ov.z = gam * (o[2] + bb4.z) + xv.z;
            ov.w = gam * (o[3] + bb4.w) + xv.w;
            *reinterpret_cast<float4*>(out + base) = ov;
        }
    }
}

// ---------------- launch ----------------
extern "C" void kernel_launch(void* const* d_in, const int* in_sizes, int n_in,
                              void* d_out, int out_size, void* d_ws, size_t ws_size,
                              hipStream_t stream) {
    const float* x  = (const float*)d_in[0];
    const float* Wk = (const float*)d_in[1];
    const float* bk = (const float*)d_in[2];
    const float* Wq = (const float*)d_in[3];
    const float* bq = (const float*)d_in[4];
    const float* Wv = (const float*)d_in[5];
    const float* bv = (const float*)d_in[6];
    const float* Wo = (const float*)d_in[7];
    const float* bo = (const float*)d_in[8];
    const float* gamma = (const float*)d_in[9];
    float* out = (float*)d_out;

    half_t* k_ws  = (half_t*)d_ws;
    half_t* q_ws  = k_ws + (size_t)BB * NN * DD;
    half_t* vT2   = q_ws + (size_t)BB * NN * DD;

    proj_kernel<<<256, 512, 0, stream>>>(x, Wk, bk, Wq, bq, Wv, bv, k_ws, q_ws, vT2);
    attn_kernel<<<256, 512, 0, stream>>>(k_ws, q_ws, vT2, x, Wo, bo, gamma, out);
}

// Round 11
// 38.887 us; speedup vs baseline: 1.6050x; 1.0384x over previous
//
#include <hip/hip_runtime.h>
#include <hip/hip_bf16.h>
#include <hip/hip_fp16.h>

// Self-attention: B=4, N=4096 (64x64 spatial), C=256, D=32.
//   proj_kernel : MFMA GEMM, 64-row blocks. k,q row-major [B*N][32] f16 (q pre-scaled
//                 by log2e); v tiled vT2[b][n/16][d][n%16].
//   attn_kernel : block = 64 q-rows, 512 threads = 8 waves k-split (512 k each),
//                 swapped-operand MFMA (S^T = K*Q^T, feat^T = V^T*P^T), 1-deep
//                 register prefetch, defer-max softmax, padded combine,
//                 MFMA epilogue (feat@Wo via Wo^T in LDS) + residual.
//   XCD-pinned scheduling: batch b -> XCDs {2b, 2b+1} (blockIdx%8 == XCD round-robin),
//   so each batch's K/V (512 KB) becomes L2-resident on its XCD pair instead of
//   streaming from Infinity Cache (the measured ~5 TB/s wall).

#define BB 4
#define NN 4096
#define CC 256
#define DD 32
#define LOG2E 1.44269504088896340736f
#define THR2 11.0f

typedef _Float16 half_t;
typedef _Float16 half2_t __attribute__((ext_vector_type(2)));
typedef _Float16 half4_t __attribute__((ext_vector_type(4)));
typedef _Float16 half8_t __attribute__((ext_vector_type(8)));
typedef float f32x4 __attribute__((ext_vector_type(4)));

#define MFMA_QK(a, b, c) __builtin_amdgcn_mfma_f32_16x16x32_f16(a, b, c, 0, 0, 0)
#define MFMA_PV(a, b, c) __builtin_amdgcn_mfma_f32_16x16x16f16(a, b, c, 0, 0, 0)

static __device__ inline float fexp2(float x) {
#if __has_builtin(__builtin_amdgcn_exp2f)
    return __builtin_amdgcn_exp2f(x);
#else
    return exp2f(x);
#endif
}

// ---------------- Kernel 1: fused QKV projection (MFMA) ----------------
// grid 256 blocks x 512 threads (8 waves); block = 64 rows of x.
// XCD-pinned: batch = (bid&7)>>1, chunk = ((bid>>3)<<1)|(bid&1).
__global__ __launch_bounds__(512) void proj_kernel(
    const float* __restrict__ x,
    const float* __restrict__ Wk, const float* __restrict__ bk,
    const float* __restrict__ Wq, const float* __restrict__ bq,
    const float* __restrict__ Wv, const float* __restrict__ bv,
    half_t* __restrict__ k_ws, half_t* __restrict__ q_ws, half_t* __restrict__ vT2)
{
    __shared__ half_t xs16[64][264];  // x tile f16 (rows 16B-aligned)
    __shared__ half_t Wt[96][264];    // [Wk|Wq|Wv]^T : Wt[wcol][kdim]

    const int t = threadIdx.x;
    const int xcd = blockIdx.x & 7, slot = blockIdx.x >> 3;
    const int bb = xcd >> 1;                      // batch 0..3
    const int c64 = (slot << 1) | (xcd & 1);      // chunk 0..63
    const int row0 = bb * NN + c64 * 64;

    // stage x tile [64][256] fp32 -> f16
    const float4* x4 = reinterpret_cast<const float4*>(x) + (size_t)row0 * 64;
    for (int idx = t; idx < 64 * 64; idx += 512) {
        int r = idx >> 6, c4 = idx & 63;
        float4 v = x4[r * 64 + c4];
        half4_t h;
        h[0] = (half_t)v.x; h[1] = (half_t)v.y; h[2] = (half_t)v.z; h[3] = (half_t)v.w;
        *reinterpret_cast<half4_t*>(&xs16[r][c4 * 4]) = h;
    }

    // stage W^T (q columns pre-scaled by log2e)
    for (int idx = t; idx < 3072; idx += 512) {
        int cp = idx & 127;           // c-pair
        int rest = idx >> 7;          // 0..23
        int d4 = (rest & 7) * 4;
        int mat = rest >> 3;          // 0:k 1:q 2:v
        const float* Wm = (mat == 0) ? Wk : ((mat == 1) ? Wq : Wv);
        const float sc = (mat == 1) ? LOG2E : 1.0f;
        float4 w0 = *reinterpret_cast<const float4*>(Wm + (2 * cp) * DD + d4);
        float4 w1 = *reinterpret_cast<const float4*>(Wm + (2 * cp + 1) * DD + d4);
        int rbase = mat * 32 + d4;
        half2_t h;
        h[0] = (half_t)(w0.x * sc); h[1] = (half_t)(w1.x * sc);
        *reinterpret_cast<half2_t*>(&Wt[rbase + 0][2 * cp]) = h;
        h[0] = (half_t)(w0.y * sc); h[1] = (half_t)(w1.y * sc);
        *reinterpret_cast<half2_t*>(&Wt[rbase + 1][2 * cp]) = h;
        h[0] = (half_t)(w0.z * sc); h[1] = (half_t)(w1.z * sc);
        *reinterpret_cast<half2_t*>(&Wt[rbase + 2][2 * cp]) = h;
        h[0] = (half_t)(w0.w * sc); h[1] = (half_t)(w1.w * sc);
        *reinterpret_cast<half2_t*>(&Wt[rbase + 3][2 * cp]) = h;
    }
    __syncthreads();

    const int w = t >> 6, lane = t & 63;
    const int c = lane & 15, g = lane >> 4;
    const int rt = w >> 1;            // row tile 0..3
    const int ct0 = (w & 1) * 3;      // col tiles ct0..ct0+2

    f32x4 acc[3];
#pragma unroll
    for (int j = 0; j < 3; ++j) acc[j] = (f32x4){0.f, 0.f, 0.f, 0.f};

#pragma unroll
    for (int kk = 0; kk < 8; ++kk) {
        const int k0 = kk * 32 + g * 8;
        half8_t bfrag = *reinterpret_cast<const half8_t*>(&xs16[rt * 16 + c][k0]);
#pragma unroll
        for (int j = 0; j < 3; ++j) {
            half8_t afrag = *reinterpret_cast<const half8_t*>(&Wt[(ct0 + j) * 16 + c][k0]);
            acc[j] = MFMA_QK(afrag, bfrag, acc[j]);
        }
    }

    // store: lane holds C[xrow = rt*16+c][wcol = ct*16+4g+i]
    const int grow = row0 + rt * 16 + c;
#pragma unroll
    for (int j = 0; j < 3; ++j) {
        const int ct = ct0 + j;
        const int mat = ct >> 1;           // 0:k 1:q 2:v
        const float* bm = (mat == 0) ? bk : ((mat == 1) ? bq : bv);
        float4 bb4 = *reinterpret_cast<const float4*>(bm + (ct & 1) * 16 + g * 4);
        if (mat < 2) {
            const float bsc = (mat == 1) ? LOG2E : 1.0f;
            half_t* dst = (mat == 0) ? k_ws : q_ws;
            half4_t h;
            h[0] = (half_t)(acc[j][0] + bb4.x * bsc);
            h[1] = (half_t)(acc[j][1] + bb4.y * bsc);
            h[2] = (half_t)(acc[j][2] + bb4.z * bsc);
            h[3] = (half_t)(acc[j][3] + bb4.w * bsc);
            *reinterpret_cast<half4_t*>(dst + (size_t)grow * DD + (ct & 1) * 16 + g * 4) = h;
        } else {
            // vT2[(row0>>4)+rt][d][n%16], d = (ct&1)*16+g*4+i, n%16 = c
            const size_t tbase = ((size_t)(row0 >> 4) + rt) * 512;
            const int d0 = (ct & 1) * 16 + g * 4;
            vT2[tbase + (size_t)(d0 + 0) * 16 + c] = (half_t)(acc[j][0] + bb4.x);
            vT2[tbase + (size_t)(d0 + 1) * 16 + c] = (half_t)(acc[j][1] + bb4.y);
            vT2[tbase + (size_t)(d0 + 2) * 16 + c] = (half_t)(acc[j][2] + bb4.z);
            vT2[tbase + (size_t)(d0 + 3) * 16 + c] = (half_t)(acc[j][3] + bb4.w);
        }
    }
}

// ---------------- Kernel 2: flash attention + output projection ----------------
// grid 256 blocks x 512 threads (8 waves). Block = 64 q rows (4 tiles/wave).
// XCD-pinned: batch = (bid&7)>>1, qb = ((bid>>3)<<1)|(bid&1).
// Wave w: k in [w*512, (w+1)*512), 2 k-tiles of 16 per iter, 16 iters, 1-deep prefetch.
__global__ __launch_bounds__(512) void attn_kernel(
    const half_t* __restrict__ k_ws, const half_t* __restrict__ q_ws,
    const half_t* __restrict__ vT2,
    const float* __restrict__ x, const float* __restrict__ Wo,
    const float* __restrict__ bo, const float* __restrict__ gamma,
    float* __restrict__ out)
{
    __shared__ float acc_l[8][64][33];    // 67.6 KB, 33-pad -> conflict-free combine
    __shared__ float m_l[8][4][16];       // 2 KB
    __shared__ float s_l[8][4][16];       // 2 KB
    __shared__ half_t feat_h[64 * 40];    // 5 KB  feat f16, 40-halves rows
    __shared__ half_t woT[256 * 40];      // 20 KB Wo^T f16: woT[c*40+d]

    const int tid = threadIdx.x;
    const int w = tid >> 6, lane = tid & 63;
    const int q = lane & 15, g = lane >> 4;
    const int xcd = blockIdx.x & 7, slot = blockIdx.x >> 3;
    const int b = xcd >> 1;                       // batch 0..3 pinned to XCD pair
    const int qb = (slot << 1) | (xcd & 1);       // 0..63
    const int q0 = qb * 64;

    // stage Wo^T as f16 (coalesced reads; 8192 elements)
#pragma unroll
    for (int it = 0; it < 16; ++it) {
        int idx = tid + it * 512;
        int c = idx & 255, d = idx >> 8;
        woT[c * 40 + d] = (half_t)Wo[d * CC + c];
    }

    // Q fragments (B-operand of S^T = K*Q^T), pre-scaled by log2e
    half8_t qf[4];
#pragma unroll
    for (int t = 0; t < 4; ++t)
        qf[t] = *reinterpret_cast<const half8_t*>(
            q_ws + (size_t)(b * NN + q0 + t * 16 + q) * DD + g * 8);

    float m[4], ssum[4];
    f32x4 accd0[4], accd1[4];
#pragma unroll
    for (int t = 0; t < 4; ++t) {
        m[t] = -3.0e38f; ssum[t] = 0.f;
        accd0[t] = (f32x4){0.f, 0.f, 0.f, 0.f};
        accd1[t] = (f32x4){0.f, 0.f, 0.f, 0.f};
    }

    const half_t* kbase = k_ws + ((size_t)b * NN + q) * DD + g * 8;
    // vT2 tile = 512 halves [d(32)][n%16]; lane reads d={q,16+q}, n%16 = g*4..+3
    const half_t* vb = vT2 + (size_t)b * 256 * 512 + q * 16 + g * 4;

    const int ktbase = w * 32;

    // prologue: iteration 0's K and V fragments
    half8_t kc0 = *reinterpret_cast<const half8_t*>(kbase + (size_t)(ktbase + 0) * 16 * DD);
    half8_t kc1 = *reinterpret_cast<const half8_t*>(kbase + (size_t)(ktbase + 1) * 16 * DD);
    half4_t va0 = *reinterpret_cast<const half4_t*>(vb + (size_t)(ktbase + 0) * 512);
    half4_t va1 = *reinterpret_cast<const half4_t*>(vb + (size_t)(ktbase + 0) * 512 + 256);
    half4_t vc0 = *reinterpret_cast<const half4_t*>(vb + (size_t)(ktbase + 1) * 512);
    half4_t vc1 = *reinterpret_cast<const half4_t*>(vb + (size_t)(ktbase + 1) * 512 + 256);

    for (int it = 0; it < 16; ++it) {
        const int kt = ktbase + it * 2;
        const int ktn = (it < 15) ? (kt + 2) : kt;

        // prefetch next iteration's K and V fragments
        half8_t kn0 = *reinterpret_cast<const half8_t*>(kbase + (size_t)(ktn + 0) * 16 * DD);
        half8_t kn1 = *reinterpret_cast<const half8_t*>(kbase + (size_t)(ktn + 1) * 16 * DD);
        half4_t wa0 = *reinterpret_cast<const half4_t*>(vb + (size_t)(ktn + 0) * 512);
        half4_t wa1 = *reinterpret_cast<const half4_t*>(vb + (size_t)(ktn + 0) * 512 + 256);
        half4_t wc0 = *reinterpret_cast<const half4_t*>(vb + (size_t)(ktn + 1) * 512);
        half4_t wc1 = *reinterpret_cast<const half4_t*>(vb + (size_t)(ktn + 1) * 512 + 256);

        // QK^T: 8 MFMAs (4 q-tiles x 2 k-tiles) on resident K
        f32x4 z = {0.f, 0.f, 0.f, 0.f};
        f32x4 s0[4], s1[4];
#pragma unroll
        for (int t = 0; t < 4; ++t) {
            s0[t] = MFMA_QK(kc0, qf[t], z);
            s1[t] = MFMA_QK(kc1, qf[t], z);
        }

        float tmax[4];
        bool need = false;
#pragma unroll
        for (int t = 0; t < 4; ++t) {
            float t0 = fmaxf(fmaxf(s0[t][0], s0[t][1]), fmaxf(s0[t][2], s0[t][3]));
            float t1 = fmaxf(fmaxf(s1[t][0], s1[t][1]), fmaxf(s1[t][2], s1[t][3]));
            tmax[t] = fmaxf(t0, t1);
            need = need || (tmax[t] > m[t] + THR2);
        }

        // defer-max: rescale only when some lane/tile exceeds headroom
        if (__any(need)) {
#pragma unroll
            for (int t = 0; t < 4; ++t) {
                float rmax = tmax[t];
                rmax = fmaxf(rmax, __shfl_xor(rmax, 16));
                rmax = fmaxf(rmax, __shfl_xor(rmax, 32));
                float mn = fmaxf(m[t], rmax);
                float sc = fexp2(m[t] - mn);
                ssum[t] *= sc;
                accd0[t] *= sc;
                accd1[t] *= sc;
                m[t] = mn;
            }
        }

        // softmax (log2 domain) + PV per q-tile
#pragma unroll
        for (int t = 0; t < 4; ++t) {
            float p00 = fexp2(s0[t][0] - m[t]), p01 = fexp2(s0[t][1] - m[t]);
            float p02 = fexp2(s0[t][2] - m[t]), p03 = fexp2(s0[t][3] - m[t]);
            float p10 = fexp2(s1[t][0] - m[t]), p11 = fexp2(s1[t][1] - m[t]);
            float p12 = fexp2(s1[t][2] - m[t]), p13 = fexp2(s1[t][3] - m[t]);
            ssum[t] += ((p00 + p01) + (p02 + p03)) + ((p10 + p11) + (p12 + p13));

            half4_t pf0, pf1;
            pf0[0] = (half_t)p00; pf0[1] = (half_t)p01; pf0[2] = (half_t)p02; pf0[3] = (half_t)p03;
            pf1[0] = (half_t)p10; pf1[1] = (half_t)p11; pf1[2] = (half_t)p12; pf1[3] = (half_t)p13;

            accd0[t] = MFMA_PV(va0, pf0, accd0[t]);
            accd1[t] = MFMA_PV(va1, pf0, accd1[t]);
            accd0[t] = MFMA_PV(vc0, pf1, accd0[t]);
            accd1[t] = MFMA_PV(vc1, pf1, accd1[t]);
        }

        kc0 = kn0; kc1 = kn1;
        va0 = wa0; va1 = wa1; vc0 = wc0; vc1 = wc1;
    }

    // fold lane-local ssum to row sums
#pragma unroll
    for (int t = 0; t < 4; ++t) {
        ssum[t] += __shfl_xor(ssum[t], 16);
        ssum[t] += __shfl_xor(ssum[t], 32);
    }

    if (lane < 16) {
#pragma unroll
        for (int t = 0; t < 4; ++t) { m_l[w][t][lane] = m[t]; s_l[w][t][lane] = ssum[t]; }
    }
#pragma unroll
    for (int t = 0; t < 4; ++t)
#pragma unroll
        for (int i = 0; i < 4; ++i) {
            acc_l[w][lane][t * 8 + i] = accd0[t][i];
            acc_l[w][lane][t * 8 + 4 + i] = accd1[t][i];
        }
    __syncthreads();

    // waves 0..3 combine the 8 k-splits; wave w handles q-tile t=w.
    if (w < 4) {
        const int t = w;
        float M = m_l[0][t][q];
#pragma unroll
        for (int ww = 1; ww < 8; ++ww) M = fmaxf(M, m_l[ww][t][q]);
        float SS = 0.f;
        float f[8] = {0.f, 0.f, 0.f, 0.f, 0.f, 0.f, 0.f, 0.f};
#pragma unroll
        for (int ww = 0; ww < 8; ++ww) {
            float sc = fexp2(m_l[ww][t][q] - M);
            SS += s_l[ww][t][q] * sc;
#pragma unroll
            for (int i = 0; i < 8; ++i) f[i] += acc_l[ww][lane][t * 8 + i] * sc;
        }
        float inv = 1.0f / SS;
        half4_t h0, h1;
#pragma unroll
        for (int i = 0; i < 4; ++i) { h0[i] = (half_t)(f[i] * inv); h1[i] = (half_t)(f[4 + i] * inv); }
        *reinterpret_cast<half4_t*>(&feat_h[(t * 16 + q) * 40 + g * 4]) = h0;
        *reinterpret_cast<half4_t*>(&feat_h[(t * 16 + q) * 40 + 16 + g * 4]) = h1;
    }
    __syncthreads();

    // ---- MFMA epilogue: O[r][c] = gamma*(feat@Wo + bo) + x ----
    const float gam = gamma[0];
#pragma unroll
    for (int j = 0; j < 2; ++j) {
        const int ct = w * 2 + j;
        half8_t kfe = *reinterpret_cast<const half8_t*>(&woT[(ct * 16 + q) * 40 + g * 8]);
        float4 bb4 = *reinterpret_cast<const float4*>(bo + ct * 16 + g * 4);
#pragma unroll
        for (int rt = 0; rt < 4; ++rt) {
            half8_t qfe = *reinterpret_cast<const half8_t*>(&feat_h[(rt * 16 + q) * 40 + g * 8]);
            f32x4 z = {0.f, 0.f, 0.f, 0.f};
            f32x4 o = MFMA_QK(kfe, qfe, z);
            const size_t base = ((size_t)b * NN + q0 + rt * 16 + q) * CC + ct * 16 + g * 4;
            float4 xv = *reinterpret_cast<const float4*>(x + base);
            float4 ov;
            ov.x = gam * (o[0] + bb4.x) + xv.x;
            ov.y = gam * (o[1] + bb4.y) + xv.y;
            ov.z = gam * (o[2] + bb4.z) + xv.z;
            ov.w = gam * (o[3] + bb4.w) + xv.w;
            *reinterpret_cast<float4*>(out + base) = ov;
        }
    }
}

// ---------------- launch ----------------
extern "C" void kernel_launch(void* const* d_in, const int* in_sizes, int n_in,
                              void* d_out, int out_size, void* d_ws, size_t ws_size,
                              hipStream_t stream) {
    const float* x  = (const float*)d_in[0];
    const float* Wk = (const float*)d_in[1];
    const float* bk = (const float*)d_in[2];
    const float* Wq = (const float*)d_in[3];
    const float* bq = (const float*)d_in[4];
    const float* Wv = (const float*)d_in[5];
    const float* bv = (const float*)d_in[6];
    const float* Wo = (const float*)d_in[7];
    const float* bo = (const float*)d_in[8];
    const float* gamma = (const float*)d_in[9];
    float* out = (float*)d_out;

    half_t* k_ws  = (half_t*)d_ws;
    half_t* q_ws  = k_ws + (size_t)BB * NN * DD;
    half_t* vT2   = q_ws + (size_t)BB * NN * DD;

    proj_kernel<<<256, 512, 0, stream>>>(x, Wk, bk, Wq, bq, Wv, bv, k_ws, q_ws, vT2);
    attn_kernel<<<256, 512, 0, stream>>>(k_ws, q_ws, vT2, x, Wo, bo, gamma, out);
}